// Round 6
// baseline (866.722 us; speedup 1.0000x reference)
//
#include <hip/hip_runtime.h>
#include <stdint.h>

typedef unsigned int uint;
typedef unsigned short ushort;

typedef float floatx4 __attribute__((ext_vector_type(4)));
typedef __bf16 bf16x8 __attribute__((ext_vector_type(8)));

#define NPB 256          // nodes per bucket (dst >> 8)
#define PART_BLOCKS 256  // blocks in hist/partition passes
#define BSLACK 4096      // per-bucket pad slack (>= 15*NPB + 16)

// ---------- bf16 helpers (RNE, bit-level) ----------
__device__ __forceinline__ ushort f2bf(float f) {
  uint u = __float_as_uint(f);
  u += 0x7fffu + ((u >> 16) & 1u);
  return (ushort)(u >> 16);
}
__device__ __forceinline__ float bf2f(uint bits) {
  return __uint_as_float(bits << 16);
}
__device__ __forceinline__ uint pack2(float a, float b) {
  return (uint)f2bf(a) | ((uint)f2bf(b) << 16);
}

// ---------- fused prep: cast x->bf16, swizzle W, zero sentinel rows ----------
__global__ void k_prep(const float* __restrict__ x, ushort* __restrict__ xb,
                       ushort* __restrict__ hb,
                       const float* __restrict__ Wl0, const float* __restrict__ Wr0,
                       const float* __restrict__ Wl, const float* __restrict__ Wr,
                       ushort* __restrict__ Wsw, int n4, int nCast, int N) {
  int b = blockIdx.x, tid = threadIdx.x;
  if (b < nCast) {                       // cast part
    int i = b * 256 + tid;
    if (i >= n4) return;
    float4 v = reinterpret_cast<const float4*>(x)[i];
    ushort4 o;
    o.x = f2bf(v.x); o.y = f2bf(v.y); o.z = f2bf(v.z); o.w = f2bf(v.w);
    reinterpret_cast<ushort4*>(xb)[i] = o;
  } else if (b < nCast + 48) {           // W swizzle part
    int t = (b - nCast) * 256 + tid;
    if (t >= 3 * 64 * 64) return;
    int lane = t & 63;
    int blk = (t >> 6) & 63;
    int l = t >> 12;
    int kb = blk >> 3, jt = blk & 7;
    int col = jt * 16 + (lane & 15);
    ushort tmp[8];
#pragma unroll
    for (int j = 0; j < 8; ++j) {
      int k = kb * 32 + (lane >> 4) * 8 + j;
      float v;
      if (k < 128) {
        v = (l == 0) ? Wl0[k * 128 + col] : Wl[(l - 1) * 16384 + k * 128 + col];
      } else {
        int k2 = k - 128;
        v = (l == 0) ? Wr0[k2 * 128 + col] : Wr[(l - 1) * 16384 + k2 * 128 + col];
      }
      tmp[j] = f2bf(v);
    }
    reinterpret_cast<uint4*>(Wsw)[t] = *reinterpret_cast<uint4*>(tmp);
  } else {                               // sentinel row N of xb and hb -> 0
    uint* xr = reinterpret_cast<uint*>(xb + (size_t)N * 128);
    uint* hr = reinterpret_cast<uint*>(hb + (size_t)N * 128);
    if (tid < 64) xr[tid] = 0;
    else if (tid < 128) hr[tid - 64] = 0;
  }
}

// ---------- bucket histogram: cnt[bucket * PART_BLOCKS + block] ----------
__global__ __launch_bounds__(256) void k_hist(const int* __restrict__ dst,
                                              int* __restrict__ cnt, int E, int nbuck) {
  __shared__ int lc[512];
  int t = threadIdx.x;
  lc[t] = 0; lc[t + 256] = 0;
  __syncthreads();
  int per = (E + PART_BLOCKS - 1) / PART_BLOCKS;
  int s = blockIdx.x * per, e = min(E, s + per);
  for (int i = s + t; i < e; i += 256) atomicAdd(&lc[dst[i] >> 8], 1);
  __syncthreads();
  if (t < nbuck) cnt[t * PART_BLOCKS + blockIdx.x] = lc[t];
  if (t + 256 < nbuck) cnt[(t + 256) * PART_BLOCKS + blockIdx.x] = lc[t + 256];
}

// ---------- scan pass A (in-place capable) ----------
__global__ void k_scan_a(const int* __restrict__ in, int* __restrict__ partial,
                         int* __restrict__ blocksums, int n) {
  __shared__ int sm[256];
  int t = threadIdx.x;
  int base = blockIdx.x * 1024 + t * 4;
  int v0 = 0, v1 = 0, v2 = 0, v3 = 0;
  if (base + 0 < n) v0 = in[base + 0];
  if (base + 1 < n) v1 = in[base + 1];
  if (base + 2 < n) v2 = in[base + 2];
  if (base + 3 < n) v3 = in[base + 3];
  int mysum = v0 + v1 + v2 + v3;
  sm[t] = mysum;
  __syncthreads();
  for (int off = 1; off < 256; off <<= 1) {
    int x = (t >= off) ? sm[t - off] : 0;
    __syncthreads();
    sm[t] += x;
    __syncthreads();
  }
  int excl = sm[t] - mysum;
  if (t == 255) blocksums[blockIdx.x] = sm[255];
  if (base + 0 < n) partial[base + 0] = excl;
  if (base + 1 < n) partial[base + 1] = excl + v0;
  if (base + 2 < n) partial[base + 2] = excl + v0 + v1;
  if (base + 3 < n) partial[base + 3] = excl + v0 + v1 + v2;
}

// ---------- parallel single-block scan of block sums (nb <= 256) ----------
__global__ void k_scan_b(int* blocksums, int nb) {
  __shared__ int sm[256];
  int t = threadIdx.x;
  int v = (t < nb) ? blocksums[t] : 0;
  sm[t] = v;
  __syncthreads();
  for (int off = 1; off < 256; off <<= 1) {
    int x = (t >= off) ? sm[t - off] : 0;
    __syncthreads();
    sm[t] += x;
    __syncthreads();
  }
  if (t < nb) blocksums[t] = sm[t] - v;  // exclusive
}

// ---------- partition edges into bucket-major packed array ----------
__global__ __launch_bounds__(256) void k_partition(const int* __restrict__ src,
                                                   const int* __restrict__ dst,
                                                   const int* __restrict__ cntm,
                                                   const int* __restrict__ blocksums,
                                                   uint* __restrict__ part, int E, int nbuck) {
  __shared__ int cur[512];
  int t = threadIdx.x;
  if (t < nbuck) {
    int idx = t * PART_BLOCKS + blockIdx.x;
    cur[t] = cntm[idx] + blocksums[idx >> 10];
  }
  if (t + 256 < nbuck) {
    int idx = (t + 256) * PART_BLOCKS + blockIdx.x;
    cur[t + 256] = cntm[idx] + blocksums[idx >> 10];
  }
  __syncthreads();
  int per = (E + PART_BLOCKS - 1) / PART_BLOCKS;
  int s = blockIdx.x * per, e = min(E, s + per);
  for (int i = s + t; i < e; i += 256) {
    int d = dst[i];
    int k = d >> 8;
    int pos = atomicAdd(&cur[k], 1);
    part[pos] = ((uint)src[i] << 8) | (uint)(d & 255);
  }
}

// ---------- per-bucket LDS counting sort -> PADDED csr (pad to x16, sentinel N) ----
__global__ __launch_bounds__(256) void k_build(const uint* __restrict__ part,
                                               const int* __restrict__ cntm,
                                               const int* __restrict__ blocksums,
                                               int* __restrict__ row_start,
                                               int* __restrict__ nchunks,
                                               float* __restrict__ inv_deg,
                                               int* __restrict__ csr_pad,
                                               int E, int N, int nbuck) {
  int k = blockIdx.x;
  __shared__ int cnt[256];
  __shared__ int sm[256];
  __shared__ int rng[2];
  int t = threadIdx.x;
  if (t == 0) {
    int i0 = k * PART_BLOCKS;
    rng[0] = cntm[i0] + blocksums[i0 >> 10];
    int i1 = (k + 1) * PART_BLOCKS;
    rng[1] = (k + 1 < nbuck) ? cntm[i1] + blocksums[i1 >> 10] : E;
  }
  cnt[t] = 0;
  __syncthreads();
  int base = rng[0], end = rng[1];
  int cbase = base + k * BSLACK;  // padded-array base
  for (int i = base + t; i < end; i += 256) atomicAdd(&cnt[part[i] & 255u], 1);
  __syncthreads();
  int a = cnt[t];
  int pa = (a + 15) & ~15;
  sm[t] = pa;
  __syncthreads();
  for (int off = 1; off < 256; off <<= 1) {
    int x = (t >= off) ? sm[t - off] : 0;
    __syncthreads();
    sm[t] += x;
    __syncthreads();
  }
  int excl = sm[t] - pa;
  cnt[t] = excl;
  int node0 = (k << 8) + t;
  if (node0 < N) {
    row_start[node0] = cbase + excl;
    nchunks[node0] = pa >> 4;
    inv_deg[node0] = 1.0f / (float)(a > 1 ? a : 1);
  }
  __syncthreads();
  for (int i = base + t; i < end; i += 256) {
    uint p = part[i];
    int pos = atomicAdd(&cnt[p & 255u], 1);
    csr_pad[cbase + pos] = (int)(p >> 8);
  }
  // pad fill with sentinel N (zero row); disjoint from sort targets
  for (int i = a; i < pa; ++i) csr_pad[cbase + excl + i] = N;
}

// ---------- fused layer: aggregate 64 nodes -> LDS A-frags -> GEMM+bias+LN+ReLU ----
// LDS mean-tile (16B chunks): idx16 = rt*256 + kbl*64 + kg*16 + (m ^ (kbl*4+kg)).
__global__ __launch_bounds__(256, 6) void k_layer(
    const ushort* __restrict__ src, const int* __restrict__ row_start,
    const int* __restrict__ nchunks, const float* __restrict__ inv_deg,
    const int* __restrict__ csr_pad, const ushort* __restrict__ Wsw_l,
    const float* __restrict__ bl, const float* __restrict__ g,
    const float* __restrict__ be, ushort* __restrict__ out_b,
    float* __restrict__ out_f, int N) {
  __shared__ ushort lA[8192];  // 16 KB: 64 rows x 128 cols bf16, fragment-swizzled
  const uint4* __restrict__ hb4 = reinterpret_cast<const uint4*>(src);
  int t = threadIdx.x, wave = t >> 6, lane = t & 63;
  int g16 = lane >> 4, l16 = lane & 15;
  int G = wave * 4 + g16;  // 16 groups; group handles 4 consecutive nodes

  // ---- phase 1: mean aggregation (16 gathers in flight per group) ----
  for (int i = 0; i < 4; ++i) {
    int nb = G * 4 + i;
    int node = blockIdx.x * 64 + nb;
    int rs = 0, nch = 0;
    float sc = 0.f;
    if (node < N) { rs = row_start[node]; nch = nchunks[node]; sc = inv_deg[node]; }
    float ax[8];
#pragma unroll
    for (int j = 0; j < 8; ++j) ax[j] = 0.f;
    int idx_next = csr_pad[rs + l16];
    for (int c = 0; c < nch; ++c) {
      int nidx = idx_next;
      idx_next = csr_pad[rs + ((c + 1) << 4) + l16];  // slack-padded, always valid
      uint4 w[16];
#pragma unroll
      for (int u = 0; u < 16; ++u) {
        int s = __shfl(nidx, (g16 << 4) + u);
        w[u] = hb4[(size_t)s * 16 + l16];
      }
#pragma unroll
      for (int u = 0; u < 16; ++u) {
        ax[0] += bf2f(w[u].x & 0xffffu); ax[1] += bf2f(w[u].x >> 16);
        ax[2] += bf2f(w[u].y & 0xffffu); ax[3] += bf2f(w[u].y >> 16);
        ax[4] += bf2f(w[u].z & 0xffffu); ax[5] += bf2f(w[u].z >> 16);
        ax[6] += bf2f(w[u].w & 0xffffu); ax[7] += bf2f(w[u].w >> 16);
      }
    }
    uint4 o;
    o.x = pack2(ax[0] * sc, ax[1] * sc);
    o.y = pack2(ax[2] * sc, ax[3] * sc);
    o.z = pack2(ax[4] * sc, ax[5] * sc);
    o.w = pack2(ax[6] * sc, ax[7] * sc);
    // lane l16 holds k-chunk l16 of node nb: kbl=l16>>2, kg=l16&3
    int idx16 = ((nb >> 4) << 8) + ((l16 >> 2) << 6) + ((l16 & 3) << 4) + ((nb & 15) ^ l16);
    *reinterpret_cast<uint4*>(&lA[idx16 * 8]) = o;
  }
  __syncthreads();

  // ---- phase 2: GEMM (K=256 = [mean|h]) + bias + LayerNorm + ReLU ----
  // wave handles row-tile rt=wave (rows wave*16..wave*16+15)
  int m = lane & 15;
  int kgp = lane >> 4;
  int koff = kgp * 8;
  size_t row0 = (size_t)(blockIdx.x * 64 + wave * 16 + m);
  const bf16x8* __restrict__ Wg = reinterpret_cast<const bf16x8*>(Wsw_l);

  floatx4 acc[8];
#pragma unroll
  for (int jt = 0; jt < 8; ++jt) acc[jt] = (floatx4){0.f, 0.f, 0.f, 0.f};

#pragma unroll
  for (int kb = 0; kb < 8; ++kb) {
    bf16x8 a0;
    if (kb < 4) {  // mean half from LDS fragments
      int i0 = (wave << 8) + (kb << 6) + (kgp << 4) + (m ^ (kb * 4 + kgp));
      a0 = *reinterpret_cast<const bf16x8*>(&lA[i0 * 8]);
    } else {       // h half direct from global
      int ke = (kb & 3) * 32 + koff;
      a0 = *reinterpret_cast<const bf16x8*>(src + row0 * 128 + ke);
    }
#pragma unroll
    for (int jt = 0; jt < 8; ++jt) {
      bf16x8 b = Wg[(kb * 8 + jt) * 64 + lane];
      acc[jt] = __builtin_amdgcn_mfma_f32_16x16x32_bf16(a0, b, acc[jt], 0, 0, 0);
    }
  }

  float blv[8], gv[8], bev[8];
#pragma unroll
  for (int jt = 0; jt < 8; ++jt) {
    int c = jt * 16 + m;
    blv[jt] = bl[c]; gv[jt] = g[c]; bev[jt] = be[c];
  }
  float s[4] = {0, 0, 0, 0}, q[4] = {0, 0, 0, 0};
#pragma unroll
  for (int jt = 0; jt < 8; ++jt) {
#pragma unroll
    for (int r = 0; r < 4; ++r) {
      float v = acc[jt][r] + blv[jt];
      acc[jt][r] = v;
      s[r] += v; q[r] += v * v;
    }
  }
#pragma unroll
  for (int off = 1; off < 16; off <<= 1) {
#pragma unroll
    for (int r = 0; r < 4; ++r) {
      s[r] += __shfl_xor(s[r], off);
      q[r] += __shfl_xor(q[r], off);
    }
  }
  int rowbase = blockIdx.x * 64 + wave * 16 + (lane >> 4) * 4;
#pragma unroll
  for (int r = 0; r < 4; ++r) {
    int row = rowbase + r;
    if (row < N) {
      float mu = s[r] * 0.0078125f;
      float var = q[r] * 0.0078125f - mu * mu;
      float rstd = rsqrtf(var + 1e-5f);
#pragma unroll
      for (int jt = 0; jt < 8; ++jt) {
        float y = (acc[jt][r] - mu) * rstd * gv[jt] + bev[jt];
        y = fmaxf(y, 0.f);
        int c = jt * 16 + m;
        if (out_f) out_f[(size_t)row * 128 + c] = y;
        else out_b[(size_t)row * 128 + c] = f2bf(y);
      }
    }
  }
}

extern "C" void kernel_launch(void* const* d_in, const int* in_sizes, int n_in,
                              void* d_out, int out_size, void* d_ws, size_t ws_size,
                              hipStream_t stream) {
  const float* x   = (const float*)d_in[0];
  const int*   ei  = (const int*)d_in[1];
  const float* Wl0 = (const float*)d_in[2];
  const float* bl0 = (const float*)d_in[3];
  const float* Wr0 = (const float*)d_in[4];
  const float* g0  = (const float*)d_in[5];
  const float* be0 = (const float*)d_in[6];
  const float* Wl  = (const float*)d_in[7];
  const float* bls = (const float*)d_in[8];
  const float* Wr  = (const float*)d_in[9];
  const float* gs  = (const float*)d_in[10];
  const float* bes = (const float*)d_in[11];

  int N = in_sizes[0] / 128;
  int E = in_sizes[1] / 2;
  int Np = (N + 127) & ~127;
  int nbuck = (N + NPB - 1) / NPB;
  const int* srcv = ei;
  const int* dstv = ei + E;

  char* p = (char*)d_ws;
  auto alloc = [&](size_t bytes) {
    char* r = p;
    p += (bytes + 255) & ~(size_t)255;
    return r;
  };
  ushort* xb  = (ushort*)alloc((size_t)(Np + 16) * 128 * 2);
  ushort* hb  = (ushort*)alloc((size_t)(Np + 16) * 128 * 2);
  ushort* Wsw = (ushort*)alloc((size_t)3 * 64 * 64 * 8 * 2);
  int*   cntm      = (int*)alloc((size_t)nbuck * PART_BLOCKS * 4);
  int*   blocksums = (int*)alloc(8192);
  int*   row_start = (int*)alloc((size_t)N * 4);
  int*   nchunks   = (int*)alloc((size_t)N * 4);
  float* inv_deg   = (float*)alloc((size_t)N * 4);
  uint*  part      = (uint*)alloc((size_t)E * 4);
  int*   csr_pad   = (int*)alloc(((size_t)E + (size_t)nbuck * BSLACK + 256) * 4);

  // CSR build (bucket radix, all atomics in LDS)
  int nscan = nbuck * PART_BLOCKS;
  int nScanBlocks = (nscan + 1023) / 1024;
  k_hist<<<PART_BLOCKS, 256, 0, stream>>>(dstv, cntm, E, nbuck);
  k_scan_a<<<nScanBlocks, 256, 0, stream>>>(cntm, cntm, blocksums, nscan);
  k_scan_b<<<1, 256, 0, stream>>>(blocksums, nScanBlocks);
  k_partition<<<PART_BLOCKS, 256, 0, stream>>>(srcv, dstv, cntm, blocksums, part, E, nbuck);
  k_build<<<nbuck, 256, 0, stream>>>(part, cntm, blocksums, row_start, nchunks, inv_deg,
                                     csr_pad, E, N, nbuck);

  int n4 = N * 32;
  int nCast = (n4 + 255) / 256;
  k_prep<<<nCast + 49, 256, 0, stream>>>(x, xb, hb, Wl0, Wr0, Wl, Wr, Wsw, n4, nCast, N);

  dim3 grid((N + 63) / 64);
  // layer 0: src=xb -> out hb (bf16)
  k_layer<<<grid, 256, 0, stream>>>(xb, row_start, nchunks, inv_deg, csr_pad,
                                    Wsw + 0 * 32768, bl0, g0, be0, hb, nullptr, N);
  // layer 1: src=hb -> out xb (bf16)
  k_layer<<<grid, 256, 0, stream>>>(hb, row_start, nchunks, inv_deg, csr_pad,
                                    Wsw + 1 * 32768, bls + 0, gs + 0, bes + 0,
                                    xb, nullptr, N);
  // layer 2: src=xb -> out d_out (f32)
  k_layer<<<grid, 256, 0, stream>>>(xb, row_start, nchunks, inv_deg, csr_pad,
                                    Wsw + 2 * 32768, bls + 128, gs + 128, bes + 128,
                                    nullptr, (float*)d_out, N);
}

// Round 7
// 415.535 us; speedup vs baseline: 2.0858x; 2.0858x over previous
//
#include <hip/hip_runtime.h>
#include <stdint.h>

typedef unsigned int uint;
typedef unsigned short ushort;

typedef float floatx4 __attribute__((ext_vector_type(4)));
typedef __bf16 bf16x8 __attribute__((ext_vector_type(8)));

#define NPB 256          // nodes per bucket (dst >> 8)
#define PART_BLOCKS 256  // blocks in hist/partition passes
#define BSLACK 4096      // per-bucket pad slack (>= 15*NPB + 16)

// ---------- bf16 helpers (RNE, bit-level) ----------
__device__ __forceinline__ ushort f2bf(float f) {
  uint u = __float_as_uint(f);
  u += 0x7fffu + ((u >> 16) & 1u);
  return (ushort)(u >> 16);
}
__device__ __forceinline__ float bf2f(uint bits) {
  return __uint_as_float(bits << 16);
}
__device__ __forceinline__ uint pack2(float a, float b) {
  return (uint)f2bf(a) | ((uint)f2bf(b) << 16);
}

// ---------- fused prep: cast x->bf16, swizzle W, zero sentinel rows ----------
__global__ void k_prep(const float* __restrict__ x, ushort* __restrict__ xb,
                       ushort* __restrict__ hb,
                       const float* __restrict__ Wl0, const float* __restrict__ Wr0,
                       const float* __restrict__ Wl, const float* __restrict__ Wr,
                       ushort* __restrict__ Wsw, int n4, int nCast, int N) {
  int b = blockIdx.x, tid = threadIdx.x;
  if (b < nCast) {                       // cast part
    int i = b * 256 + tid;
    if (i >= n4) return;
    float4 v = reinterpret_cast<const float4*>(x)[i];
    ushort4 o;
    o.x = f2bf(v.x); o.y = f2bf(v.y); o.z = f2bf(v.z); o.w = f2bf(v.w);
    reinterpret_cast<ushort4*>(xb)[i] = o;
  } else if (b < nCast + 48) {           // W swizzle part
    int t = (b - nCast) * 256 + tid;
    if (t >= 3 * 64 * 64) return;
    int lane = t & 63;
    int blk = (t >> 6) & 63;
    int l = t >> 12;
    int kb = blk >> 3, jt = blk & 7;
    int col = jt * 16 + (lane & 15);
    ushort tmp[8];
#pragma unroll
    for (int j = 0; j < 8; ++j) {
      int k = kb * 32 + (lane >> 4) * 8 + j;
      float v;
      if (k < 128) {
        v = (l == 0) ? Wl0[k * 128 + col] : Wl[(l - 1) * 16384 + k * 128 + col];
      } else {
        int k2 = k - 128;
        v = (l == 0) ? Wr0[k2 * 128 + col] : Wr[(l - 1) * 16384 + k2 * 128 + col];
      }
      tmp[j] = f2bf(v);
    }
    reinterpret_cast<uint4*>(Wsw)[t] = *reinterpret_cast<uint4*>(tmp);
  } else {                               // sentinel row N of xb and hb -> 0
    uint* xr = reinterpret_cast<uint*>(xb + (size_t)N * 128);
    uint* hr = reinterpret_cast<uint*>(hb + (size_t)N * 128);
    if (tid < 64) xr[tid] = 0;
    else if (tid < 128) hr[tid - 64] = 0;
  }
}

// ---------- bucket histogram: cnt[bucket * PART_BLOCKS + block] ----------
__global__ __launch_bounds__(256) void k_hist(const int* __restrict__ dst,
                                              int* __restrict__ cnt, int E, int nbuck) {
  __shared__ int lc[512];
  int t = threadIdx.x;
  lc[t] = 0; lc[t + 256] = 0;
  __syncthreads();
  int per = (E + PART_BLOCKS - 1) / PART_BLOCKS;
  int s = blockIdx.x * per, e = min(E, s + per);
  for (int i = s + t; i < e; i += 256) atomicAdd(&lc[dst[i] >> 8], 1);
  __syncthreads();
  if (t < nbuck) cnt[t * PART_BLOCKS + blockIdx.x] = lc[t];
  if (t + 256 < nbuck) cnt[(t + 256) * PART_BLOCKS + blockIdx.x] = lc[t + 256];
}

// ---------- scan pass A (in-place): per-1024-chunk exclusive scan + chunk sums ----------
__global__ void k_scan_a(const int* __restrict__ in, int* __restrict__ partial,
                         int* __restrict__ blocksums, int n) {
  __shared__ int sm[256];
  int t = threadIdx.x;
  int base = blockIdx.x * 1024 + t * 4;
  int v0 = 0, v1 = 0, v2 = 0, v3 = 0;
  if (base + 0 < n) v0 = in[base + 0];
  if (base + 1 < n) v1 = in[base + 1];
  if (base + 2 < n) v2 = in[base + 2];
  if (base + 3 < n) v3 = in[base + 3];
  int mysum = v0 + v1 + v2 + v3;
  sm[t] = mysum;
  __syncthreads();
  for (int off = 1; off < 256; off <<= 1) {
    int x = (t >= off) ? sm[t - off] : 0;
    __syncthreads();
    sm[t] += x;
    __syncthreads();
  }
  int excl = sm[t] - mysum;
  if (t == 255) blocksums[blockIdx.x] = sm[255];
  if (base + 0 < n) partial[base + 0] = excl;
  if (base + 1 < n) partial[base + 1] = excl + v0;
  if (base + 2 < n) partial[base + 2] = excl + v0 + v1;
  if (base + 3 < n) partial[base + 3] = excl + v0 + v1 + v2;
}

// ---------- in-LDS exclusive scan of chunk sums (nb <= 256), result in sbs ----------
__device__ __forceinline__ void lds_scan_blocksums(const int* __restrict__ blocksums,
                                                   int* sbs, int nb, int t) {
  int v = (t < nb) ? blocksums[t] : 0;
  sbs[t] = v;
  __syncthreads();
  for (int off = 1; off < 256; off <<= 1) {
    int x = (t >= off) ? sbs[t - off] : 0;
    __syncthreads();
    sbs[t] += x;
    __syncthreads();
  }
  int incl = sbs[t];
  __syncthreads();
  sbs[t] = incl - v;  // exclusive
  __syncthreads();
}

// ---------- partition edges into bucket-major packed array ----------
__global__ __launch_bounds__(256) void k_partition(const int* __restrict__ src,
                                                   const int* __restrict__ dst,
                                                   const int* __restrict__ cntm,
                                                   const int* __restrict__ blocksums,
                                                   uint* __restrict__ part, int E,
                                                   int nbuck, int nb) {
  __shared__ int sbs[256];
  __shared__ int cur[512];
  int t = threadIdx.x;
  lds_scan_blocksums(blocksums, sbs, nb, t);
  if (t < nbuck) {
    int idx = t * PART_BLOCKS + blockIdx.x;
    cur[t] = cntm[idx] + sbs[idx >> 10];
  }
  if (t + 256 < nbuck) {
    int idx = (t + 256) * PART_BLOCKS + blockIdx.x;
    cur[t + 256] = cntm[idx] + sbs[idx >> 10];
  }
  __syncthreads();
  int per = (E + PART_BLOCKS - 1) / PART_BLOCKS;
  int s = blockIdx.x * per, e = min(E, s + per);
  for (int i = s + t; i < e; i += 256) {
    int d = dst[i];
    int k = d >> 8;
    int pos = atomicAdd(&cur[k], 1);
    part[pos] = ((uint)src[i] << 8) | (uint)(d & 255);
  }
}

// ---------- per-bucket LDS counting sort -> PADDED csr (pad to x16, sentinel N) ----
__global__ __launch_bounds__(256) void k_build(const uint* __restrict__ part,
                                               const int* __restrict__ cntm,
                                               const int* __restrict__ blocksums,
                                               int* __restrict__ row_start,
                                               int* __restrict__ nchunks,
                                               float* __restrict__ inv_deg,
                                               int* __restrict__ csr_pad,
                                               int E, int N, int nbuck, int nb) {
  int k = blockIdx.x;
  __shared__ int sbs[256];
  __shared__ int cnt[256];
  __shared__ int sm[256];
  int t = threadIdx.x;
  lds_scan_blocksums(blocksums, sbs, nb, t);
  int i0 = k * PART_BLOCKS;
  int base = cntm[i0] + sbs[i0 >> 10];
  int end;
  if (k + 1 < nbuck) {
    int i1 = (k + 1) * PART_BLOCKS;
    end = cntm[i1] + sbs[i1 >> 10];
  } else {
    end = E;
  }
  cnt[t] = 0;
  __syncthreads();
  int cbase = base + k * BSLACK;  // padded-array base
  for (int i = base + t; i < end; i += 256) atomicAdd(&cnt[part[i] & 255u], 1);
  __syncthreads();
  int a = cnt[t];
  int pa = (a + 15) & ~15;
  sm[t] = pa;
  __syncthreads();
  for (int off = 1; off < 256; off <<= 1) {
    int x = (t >= off) ? sm[t - off] : 0;
    __syncthreads();
    sm[t] += x;
    __syncthreads();
  }
  int excl = sm[t] - pa;
  cnt[t] = excl;
  int node0 = (k << 8) + t;
  if (node0 < N) {
    row_start[node0] = cbase + excl;
    nchunks[node0] = pa >> 4;
    inv_deg[node0] = 1.0f / (float)(a > 1 ? a : 1);
  }
  __syncthreads();
  for (int i = base + t; i < end; i += 256) {
    uint p = part[i];
    int pos = atomicAdd(&cnt[p & 255u], 1);
    csr_pad[cbase + pos] = (int)(p >> 8);
  }
  // pad fill with sentinel N (zero row); disjoint from sort targets
  for (int i = a; i < pa; ++i) csr_pad[cbase + excl + i] = N;
}

// ---------- fused layer: aggregate 64 nodes -> LDS A-frags -> GEMM+bias+LN+ReLU ----
// Gather uses two batches of 8 in-flight loads (caps live VGPRs, no spill).
// LDS mean-tile (16B chunks): idx16 = rt*256 + kbl*64 + kg*16 + (m ^ (kbl*4+kg)).
__global__ __launch_bounds__(256, 4) void k_layer(
    const ushort* __restrict__ src, const int* __restrict__ row_start,
    const int* __restrict__ nchunks, const float* __restrict__ inv_deg,
    const int* __restrict__ csr_pad, const ushort* __restrict__ Wsw_l,
    const float* __restrict__ bl, const float* __restrict__ g,
    const float* __restrict__ be, ushort* __restrict__ out_b,
    float* __restrict__ out_f, int N) {
  __shared__ ushort lA[8192];  // 16 KB: 64 rows x 128 cols bf16, fragment-swizzled
  const uint4* __restrict__ hb4 = reinterpret_cast<const uint4*>(src);
  int t = threadIdx.x, wave = t >> 6, lane = t & 63;
  int g16 = lane >> 4, l16 = lane & 15;
  int G = wave * 4 + g16;  // 16 groups; group handles 4 consecutive nodes

  // ---- phase 1: mean aggregation ----
  for (int i = 0; i < 4; ++i) {
    int nb_ = G * 4 + i;
    int node = blockIdx.x * 64 + nb_;
    int rs = 0, nch = 0;
    float sc = 0.f;
    if (node < N) { rs = row_start[node]; nch = nchunks[node]; sc = inv_deg[node]; }
    float ax[8];
#pragma unroll
    for (int j = 0; j < 8; ++j) ax[j] = 0.f;
    int idx_next = csr_pad[rs + l16];
    for (int c = 0; c < nch; ++c) {
      int nidx = idx_next;
      idx_next = csr_pad[rs + ((c + 1) << 4) + l16];  // slack-padded, always valid
      uint4 w[8];
#pragma unroll
      for (int u = 0; u < 8; ++u) {
        int s = __shfl(nidx, (g16 << 4) + u);
        w[u] = hb4[(size_t)s * 16 + l16];
      }
#pragma unroll
      for (int u = 0; u < 8; ++u) {
        ax[0] += bf2f(w[u].x & 0xffffu); ax[1] += bf2f(w[u].x >> 16);
        ax[2] += bf2f(w[u].y & 0xffffu); ax[3] += bf2f(w[u].y >> 16);
        ax[4] += bf2f(w[u].z & 0xffffu); ax[5] += bf2f(w[u].z >> 16);
        ax[6] += bf2f(w[u].w & 0xffffu); ax[7] += bf2f(w[u].w >> 16);
      }
#pragma unroll
      for (int u = 0; u < 8; ++u) {
        int s = __shfl(nidx, (g16 << 4) + 8 + u);
        w[u] = hb4[(size_t)s * 16 + l16];
      }
#pragma unroll
      for (int u = 0; u < 8; ++u) {
        ax[0] += bf2f(w[u].x & 0xffffu); ax[1] += bf2f(w[u].x >> 16);
        ax[2] += bf2f(w[u].y & 0xffffu); ax[3] += bf2f(w[u].y >> 16);
        ax[4] += bf2f(w[u].z & 0xffffu); ax[5] += bf2f(w[u].z >> 16);
        ax[6] += bf2f(w[u].w & 0xffffu); ax[7] += bf2f(w[u].w >> 16);
      }
    }
    uint4 o;
    o.x = pack2(ax[0] * sc, ax[1] * sc);
    o.y = pack2(ax[2] * sc, ax[3] * sc);
    o.z = pack2(ax[4] * sc, ax[5] * sc);
    o.w = pack2(ax[6] * sc, ax[7] * sc);
    // lane l16 holds k-chunk l16 of node nb_: kbl=l16>>2, kg=l16&3
    int idx16 = ((nb_ >> 4) << 8) + ((l16 >> 2) << 6) + ((l16 & 3) << 4) + ((nb_ & 15) ^ l16);
    *reinterpret_cast<uint4*>(&lA[idx16 * 8]) = o;
  }
  __syncthreads();

  // ---- phase 2: GEMM (K=256 = [mean|h]) + bias + LayerNorm + ReLU ----
  int m = lane & 15;
  int kgp = lane >> 4;
  int koff = kgp * 8;
  size_t row0 = (size_t)(blockIdx.x * 64 + wave * 16 + m);
  const bf16x8* __restrict__ Wg = reinterpret_cast<const bf16x8*>(Wsw_l);

  floatx4 acc[8];
#pragma unroll
  for (int jt = 0; jt < 8; ++jt) acc[jt] = (floatx4){0.f, 0.f, 0.f, 0.f};

#pragma unroll
  for (int kb = 0; kb < 8; ++kb) {
    bf16x8 a0;
    if (kb < 4) {  // mean half from LDS fragments
      int i0 = (wave << 8) + (kb << 6) + (kgp << 4) + (m ^ (kb * 4 + kgp));
      a0 = *reinterpret_cast<const bf16x8*>(&lA[i0 * 8]);
    } else {       // h half direct from global
      int ke = (kb & 3) * 32 + koff;
      a0 = *reinterpret_cast<const bf16x8*>(src + row0 * 128 + ke);
    }
#pragma unroll
    for (int jt = 0; jt < 8; ++jt) {
      bf16x8 b = Wg[(kb * 8 + jt) * 64 + lane];
      acc[jt] = __builtin_amdgcn_mfma_f32_16x16x32_bf16(a0, b, acc[jt], 0, 0, 0);
    }
  }

  float blv[8], gv[8], bev[8];
#pragma unroll
  for (int jt = 0; jt < 8; ++jt) {
    int c = jt * 16 + m;
    blv[jt] = bl[c]; gv[jt] = g[c]; bev[jt] = be[c];
  }
  float s[4] = {0, 0, 0, 0}, q[4] = {0, 0, 0, 0};
#pragma unroll
  for (int jt = 0; jt < 8; ++jt) {
#pragma unroll
    for (int r = 0; r < 4; ++r) {
      float v = acc[jt][r] + blv[jt];
      acc[jt][r] = v;
      s[r] += v; q[r] += v * v;
    }
  }
#pragma unroll
  for (int off = 1; off < 16; off <<= 1) {
#pragma unroll
    for (int r = 0; r < 4; ++r) {
      s[r] += __shfl_xor(s[r], off);
      q[r] += __shfl_xor(q[r], off);
    }
  }
  int rowbase = blockIdx.x * 64 + wave * 16 + (lane >> 4) * 4;
#pragma unroll
  for (int r = 0; r < 4; ++r) {
    int row = rowbase + r;
    if (row < N) {
      float mu = s[r] * 0.0078125f;
      float var = q[r] * 0.0078125f - mu * mu;
      float rstd = rsqrtf(var + 1e-5f);
#pragma unroll
      for (int jt = 0; jt < 8; ++jt) {
        float y = (acc[jt][r] - mu) * rstd * gv[jt] + bev[jt];
        y = fmaxf(y, 0.f);
        int c = jt * 16 + m;
        if (out_f) out_f[(size_t)row * 128 + c] = y;
        else out_b[(size_t)row * 128 + c] = f2bf(y);
      }
    }
  }
}

extern "C" void kernel_launch(void* const* d_in, const int* in_sizes, int n_in,
                              void* d_out, int out_size, void* d_ws, size_t ws_size,
                              hipStream_t stream) {
  const float* x   = (const float*)d_in[0];
  const int*   ei  = (const int*)d_in[1];
  const float* Wl0 = (const float*)d_in[2];
  const float* bl0 = (const float*)d_in[3];
  const float* Wr0 = (const float*)d_in[4];
  const float* g0  = (const float*)d_in[5];
  const float* be0 = (const float*)d_in[6];
  const float* Wl  = (const float*)d_in[7];
  const float* bls = (const float*)d_in[8];
  const float* Wr  = (const float*)d_in[9];
  const float* gs  = (const float*)d_in[10];
  const float* bes = (const float*)d_in[11];

  int N = in_sizes[0] / 128;
  int E = in_sizes[1] / 2;
  int Np = (N + 127) & ~127;
  int nbuck = (N + NPB - 1) / NPB;
  const int* srcv = ei;
  const int* dstv = ei + E;

  char* p = (char*)d_ws;
  auto alloc = [&](size_t bytes) {
    char* r = p;
    p += (bytes + 255) & ~(size_t)255;
    return r;
  };
  ushort* xb  = (ushort*)alloc((size_t)(Np + 16) * 128 * 2);
  ushort* hb  = (ushort*)alloc((size_t)(Np + 16) * 128 * 2);
  ushort* Wsw = (ushort*)alloc((size_t)3 * 64 * 64 * 8 * 2);
  int*   cntm      = (int*)alloc((size_t)nbuck * PART_BLOCKS * 4);
  int*   blocksums = (int*)alloc(8192);
  int*   row_start = (int*)alloc((size_t)N * 4);
  int*   nchunks   = (int*)alloc((size_t)N * 4);
  float* inv_deg   = (float*)alloc((size_t)N * 4);
  uint*  part      = (uint*)alloc((size_t)E * 4);
  int*   csr_pad   = (int*)alloc(((size_t)E + (size_t)nbuck * BSLACK + 256) * 4);

  // CSR build (bucket radix, all atomics in LDS)
  int nscan = nbuck * PART_BLOCKS;
  int nScanBlocks = (nscan + 1023) / 1024;
  k_hist<<<PART_BLOCKS, 256, 0, stream>>>(dstv, cntm, E, nbuck);
  k_scan_a<<<nScanBlocks, 256, 0, stream>>>(cntm, cntm, blocksums, nscan);
  k_partition<<<PART_BLOCKS, 256, 0, stream>>>(srcv, dstv, cntm, blocksums, part, E,
                                               nbuck, nScanBlocks);
  k_build<<<nbuck, 256, 0, stream>>>(part, cntm, blocksums, row_start, nchunks, inv_deg,
                                     csr_pad, E, N, nbuck, nScanBlocks);

  int n4 = N * 32;
  int nCast = (n4 + 255) / 256;
  k_prep<<<nCast + 49, 256, 0, stream>>>(x, xb, hb, Wl0, Wr0, Wl, Wr, Wsw, n4, nCast, N);

  dim3 grid((N + 63) / 64);
  // layer 0: src=xb -> out hb (bf16)
  k_layer<<<grid, 256, 0, stream>>>(xb, row_start, nchunks, inv_deg, csr_pad,
                                    Wsw + 0 * 32768, bl0, g0, be0, hb, nullptr, N);
  // layer 1: src=hb -> out xb (bf16)
  k_layer<<<grid, 256, 0, stream>>>(hb, row_start, nchunks, inv_deg, csr_pad,
                                    Wsw + 1 * 32768, bls + 0, gs + 0, bes + 0,
                                    xb, nullptr, N);
  // layer 2: src=xb -> out d_out (f32)
  k_layer<<<grid, 256, 0, stream>>>(xb, row_start, nchunks, inv_deg, csr_pad,
                                    Wsw + 2 * 32768, bls + 128, gs + 128, bes + 128,
                                    nullptr, (float*)d_out, N);
}

// Round 9
// 410.925 us; speedup vs baseline: 2.1092x; 1.0112x over previous
//
#include <hip/hip_runtime.h>
#include <stdint.h>

typedef unsigned int uint;
typedef unsigned short ushort;

typedef float floatx4 __attribute__((ext_vector_type(4)));
typedef __bf16 bf16x8 __attribute__((ext_vector_type(8)));

#define NPB 256          // nodes per bucket (dst >> 8)
#define PART_BLOCKS 256  // blocks in hist/partition passes
#define BSLACK 4096      // per-bucket pad slack (>= 15*NPB + 16)

// ---------- bf16 helpers (RNE, bit-level) ----------
__device__ __forceinline__ ushort f2bf(float f) {
  uint u = __float_as_uint(f);
  u += 0x7fffu + ((u >> 16) & 1u);
  return (ushort)(u >> 16);
}
__device__ __forceinline__ float bf2f(uint bits) {
  return __uint_as_float(bits << 16);
}
__device__ __forceinline__ uint pack2(float a, float b) {
  return (uint)f2bf(a) | ((uint)f2bf(b) << 16);
}

// ---------- fused prep: cast x->bf16, swizzle W, zero sentinels, bucket hist ----------
__global__ __launch_bounds__(256) void k_prep(
    const float* __restrict__ x, ushort* __restrict__ xb, ushort* __restrict__ hb,
    const float* __restrict__ Wl0, const float* __restrict__ Wr0,
    const float* __restrict__ Wl, const float* __restrict__ Wr,
    ushort* __restrict__ Wsw, const int* __restrict__ dst, int* __restrict__ cnt,
    int E, int n4, int nCast, int N, int nbuck) {
  __shared__ int lc[512];
  int b = blockIdx.x, tid = threadIdx.x;
  if (b < nCast) {                       // cast part
    int i = b * 256 + tid;
    if (i >= n4) return;
    float4 v = reinterpret_cast<const float4*>(x)[i];
    ushort4 o;
    o.x = f2bf(v.x); o.y = f2bf(v.y); o.z = f2bf(v.z); o.w = f2bf(v.w);
    reinterpret_cast<ushort4*>(xb)[i] = o;
  } else if (b < nCast + 48) {           // W swizzle part
    int t = (b - nCast) * 256 + tid;
    if (t >= 3 * 64 * 64) return;
    int lane = t & 63;
    int blk = (t >> 6) & 63;
    int l = t >> 12;
    int kb = blk >> 3, jt = blk & 7;
    int col = jt * 16 + (lane & 15);
    ushort tmp[8];
#pragma unroll
    for (int j = 0; j < 8; ++j) {
      int k = kb * 32 + (lane >> 4) * 8 + j;
      float v;
      if (k < 128) {
        v = (l == 0) ? Wl0[k * 128 + col] : Wl[(l - 1) * 16384 + k * 128 + col];
      } else {
        int k2 = k - 128;
        v = (l == 0) ? Wr0[k2 * 128 + col] : Wr[(l - 1) * 16384 + k2 * 128 + col];
      }
      tmp[j] = f2bf(v);
    }
    reinterpret_cast<uint4*>(Wsw)[t] = *reinterpret_cast<uint4*>(tmp);
  } else if (b == nCast + 48) {          // sentinel row N of xb and hb -> 0
    uint* xr = reinterpret_cast<uint*>(xb + (size_t)N * 128);
    uint* hr = reinterpret_cast<uint*>(hb + (size_t)N * 128);
    if (tid < 64) xr[tid] = 0;
    else if (tid < 128) hr[tid - 64] = 0;
  } else {                               // bucket histogram part
    int hb_ = b - (nCast + 49);
    lc[tid] = 0; lc[tid + 256] = 0;
    __syncthreads();
    int per = (E + PART_BLOCKS - 1) / PART_BLOCKS;
    int s = hb_ * per, e = min(E, s + per);
    for (int i = s + tid; i < e; i += 256) atomicAdd(&lc[dst[i] >> 8], 1);
    __syncthreads();
    if (tid < nbuck) cnt[tid * PART_BLOCKS + hb_] = lc[tid];
    if (tid + 256 < nbuck) cnt[(tid + 256) * PART_BLOCKS + hb_] = lc[tid + 256];
  }
}

// ---------- scan pass A (in-place): per-1024-chunk exclusive scan + chunk sums ----------
__global__ void k_scan_a(const int* __restrict__ in, int* __restrict__ partial,
                         int* __restrict__ blocksums, int n) {
  __shared__ int sm[256];
  int t = threadIdx.x;
  int base = blockIdx.x * 1024 + t * 4;
  int v0 = 0, v1 = 0, v2 = 0, v3 = 0;
  if (base + 0 < n) v0 = in[base + 0];
  if (base + 1 < n) v1 = in[base + 1];
  if (base + 2 < n) v2 = in[base + 2];
  if (base + 3 < n) v3 = in[base + 3];
  int mysum = v0 + v1 + v2 + v3;
  sm[t] = mysum;
  __syncthreads();
  for (int off = 1; off < 256; off <<= 1) {
    int x = (t >= off) ? sm[t - off] : 0;
    __syncthreads();
    sm[t] += x;
    __syncthreads();
  }
  int excl = sm[t] - mysum;
  if (t == 255) blocksums[blockIdx.x] = sm[255];
  if (base + 0 < n) partial[base + 0] = excl;
  if (base + 1 < n) partial[base + 1] = excl + v0;
  if (base + 2 < n) partial[base + 2] = excl + v0 + v1;
  if (base + 3 < n) partial[base + 3] = excl + v0 + v1 + v2;
}

// ---------- in-LDS exclusive scan of chunk sums (nb <= 256), result in sbs ----------
__device__ __forceinline__ void lds_scan_blocksums(const int* __restrict__ blocksums,
                                                   int* sbs, int nb, int t) {
  int v = (t < nb) ? blocksums[t] : 0;
  sbs[t] = v;
  __syncthreads();
  for (int off = 1; off < 256; off <<= 1) {
    int x = (t >= off) ? sbs[t - off] : 0;
    __syncthreads();
    sbs[t] += x;
    __syncthreads();
  }
  int incl = sbs[t];
  __syncthreads();
  sbs[t] = incl - v;  // exclusive
  __syncthreads();
}

// ---------- partition edges into bucket-major packed array ----------
__global__ __launch_bounds__(256) void k_partition(const int* __restrict__ src,
                                                   const int* __restrict__ dst,
                                                   const int* __restrict__ cntm,
                                                   const int* __restrict__ blocksums,
                                                   uint* __restrict__ part, int E,
                                                   int nbuck, int nb) {
  __shared__ int sbs[256];
  __shared__ int cur[512];
  int t = threadIdx.x;
  lds_scan_blocksums(blocksums, sbs, nb, t);
  if (t < nbuck) {
    int idx = t * PART_BLOCKS + blockIdx.x;
    cur[t] = cntm[idx] + sbs[idx >> 10];
  }
  if (t + 256 < nbuck) {
    int idx = (t + 256) * PART_BLOCKS + blockIdx.x;
    cur[t + 256] = cntm[idx] + sbs[idx >> 10];
  }
  __syncthreads();
  int per = (E + PART_BLOCKS - 1) / PART_BLOCKS;
  int s = blockIdx.x * per, e = min(E, s + per);
  for (int i = s + t; i < e; i += 256) {
    int d = dst[i];
    int k = d >> 8;
    int pos = atomicAdd(&cur[k], 1);
    part[pos] = ((uint)src[i] << 8) | (uint)(d & 255);
  }
}

// ---------- per-bucket LDS counting sort -> PADDED csr (pad to x16, sentinel N) ----
__global__ __launch_bounds__(256) void k_build(const uint* __restrict__ part,
                                               const int* __restrict__ cntm,
                                               const int* __restrict__ blocksums,
                                               int* __restrict__ row_start,
                                               int* __restrict__ nchunks,
                                               float* __restrict__ inv_deg,
                                               int* __restrict__ csr_pad,
                                               int E, int N, int nbuck, int nb) {
  int k = blockIdx.x;
  __shared__ int sbs[256];
  __shared__ int cnt[256];
  __shared__ int sm[256];
  int t = threadIdx.x;
  lds_scan_blocksums(blocksums, sbs, nb, t);
  int i0 = k * PART_BLOCKS;
  int base = cntm[i0] + sbs[i0 >> 10];
  int end;
  if (k + 1 < nbuck) {
    int i1 = (k + 1) * PART_BLOCKS;
    end = cntm[i1] + sbs[i1 >> 10];
  } else {
    end = E;
  }
  cnt[t] = 0;
  __syncthreads();
  int cbase = base + k * BSLACK;  // padded-array base
  for (int i = base + t; i < end; i += 256) atomicAdd(&cnt[part[i] & 255u], 1);
  __syncthreads();
  int a = cnt[t];
  int pa = (a + 15) & ~15;
  sm[t] = pa;
  __syncthreads();
  for (int off = 1; off < 256; off <<= 1) {
    int x = (t >= off) ? sm[t - off] : 0;
    __syncthreads();
    sm[t] += x;
    __syncthreads();
  }
  int excl = sm[t] - pa;
  cnt[t] = excl;
  int node0 = (k << 8) + t;
  if (node0 < N) {
    row_start[node0] = cbase + excl;
    nchunks[node0] = pa >> 4;
    inv_deg[node0] = 1.0f / (float)(a > 1 ? a : 1);
  }
  __syncthreads();
  for (int i = base + t; i < end; i += 256) {
    uint p = part[i];
    int pos = atomicAdd(&cnt[p & 255u], 1);
    csr_pad[cbase + pos] = (int)(p >> 8);
  }
  // pad fill with sentinel N (zero row); disjoint from sort targets
  for (int i = a; i < pa; ++i) csr_pad[cbase + excl + i] = N;
}

// ---------- fused layer: aggregate 64 nodes -> LDS A-frags -> GEMM+bias+LN+ReLU ----
// waves_per_eu(4,4): grid is only ~6 blocks/CU deep, so tell the scheduler the true
// occupancy target and let it keep all 16 gather loads in flight (128-VGPR budget).
// LDS mean-tile (16B chunks): idx16 = rt*256 + kbl*64 + kg*16 + (m ^ (kbl*4+kg)).
__attribute__((amdgpu_waves_per_eu(4, 4)))
__global__ __launch_bounds__(256) void k_layer(
    const ushort* __restrict__ src, const int* __restrict__ row_start,
    const int* __restrict__ nchunks, const float* __restrict__ inv_deg,
    const int* __restrict__ csr_pad, const ushort* __restrict__ Wsw_l,
    const float* __restrict__ bl, const float* __restrict__ g,
    const float* __restrict__ be, ushort* __restrict__ out_b,
    float* __restrict__ out_f, int N) {
  __shared__ ushort lA[8192];  // 16 KB: mean frags, then reused as epilogue staging
  const uint4* __restrict__ hb4 = reinterpret_cast<const uint4*>(src);
  int t = threadIdx.x, wave = t >> 6, lane = t & 63;
  int g16 = lane >> 4, l16 = lane & 15;
  int G = wave * 4 + g16;  // 16 groups; group handles 4 consecutive nodes

  // ---- phase 1: mean aggregation (16 gathers in flight per group) ----
  for (int i = 0; i < 4; ++i) {
    int nb_ = G * 4 + i;
    int node = blockIdx.x * 64 + nb_;
    int rs = 0, nch = 0;
    float sc = 0.f;
    if (node < N) { rs = row_start[node]; nch = nchunks[node]; sc = inv_deg[node]; }
    float ax[8];
#pragma unroll
    for (int j = 0; j < 8; ++j) ax[j] = 0.f;
    int idx_next = csr_pad[rs + l16];
    for (int c = 0; c < nch; ++c) {
      int nidx = idx_next;
      idx_next = csr_pad[rs + ((c + 1) << 4) + l16];  // slack-padded, always valid
      uint4 w[16];
#pragma unroll
      for (int u = 0; u < 16; ++u) {
        int s = __shfl(nidx, (g16 << 4) + u);
        w[u] = hb4[(size_t)s * 16 + l16];
      }
#pragma unroll
      for (int u = 0; u < 16; ++u) {
        ax[0] += bf2f(w[u].x & 0xffffu); ax[1] += bf2f(w[u].x >> 16);
        ax[2] += bf2f(w[u].y & 0xffffu); ax[3] += bf2f(w[u].y >> 16);
        ax[4] += bf2f(w[u].z & 0xffffu); ax[5] += bf2f(w[u].z >> 16);
        ax[6] += bf2f(w[u].w & 0xffffu); ax[7] += bf2f(w[u].w >> 16);
      }
    }
    uint4 o;
    o.x = pack2(ax[0] * sc, ax[1] * sc);
    o.y = pack2(ax[2] * sc, ax[3] * sc);
    o.z = pack2(ax[4] * sc, ax[5] * sc);
    o.w = pack2(ax[6] * sc, ax[7] * sc);
    // lane l16 holds k-chunk l16 of node nb_: kbl=l16>>2, kg=l16&3
    int idx16 = ((nb_ >> 4) << 8) + ((l16 >> 2) << 6) + ((l16 & 3) << 4) + ((nb_ & 15) ^ l16);
    *reinterpret_cast<uint4*>(&lA[idx16 * 8]) = o;
  }
  __syncthreads();

  // ---- phase 2: GEMM (K=256 = [mean|h]) + bias + LayerNorm + ReLU ----
  int m = lane & 15;
  int kgp = lane >> 4;
  int koff = kgp * 8;
  size_t row0 = (size_t)(blockIdx.x * 64 + wave * 16 + m);
  const bf16x8* __restrict__ Wg = reinterpret_cast<const bf16x8*>(Wsw_l);

  floatx4 acc[8];
#pragma unroll
  for (int jt = 0; jt < 8; ++jt) acc[jt] = (floatx4){0.f, 0.f, 0.f, 0.f};

#pragma unroll
  for (int kb = 0; kb < 8; ++kb) {
    bf16x8 a0;
    if (kb < 4) {  // mean half from LDS fragments
      int i0 = (wave << 8) + (kb << 6) + (kgp << 4) + (m ^ (kb * 4 + kgp));
      a0 = *reinterpret_cast<const bf16x8*>(&lA[i0 * 8]);
    } else {       // h half direct from global
      int ke = (kb & 3) * 32 + koff;
      a0 = *reinterpret_cast<const bf16x8*>(src + row0 * 128 + ke);
    }
#pragma unroll
    for (int jt = 0; jt < 8; ++jt) {
      bf16x8 b = Wg[(kb * 8 + jt) * 64 + lane];
      acc[jt] = __builtin_amdgcn_mfma_f32_16x16x32_bf16(a0, b, acc[jt], 0, 0, 0);
    }
  }

  float blv[8], gv[8], bev[8];
#pragma unroll
  for (int jt = 0; jt < 8; ++jt) {
    int c = jt * 16 + m;
    blv[jt] = bl[c]; gv[jt] = g[c]; bev[jt] = be[c];
  }
  float s[4] = {0, 0, 0, 0}, q[4] = {0, 0, 0, 0};
#pragma unroll
  for (int jt = 0; jt < 8; ++jt) {
#pragma unroll
    for (int r = 0; r < 4; ++r) {
      float v = acc[jt][r] + blv[jt];
      acc[jt][r] = v;
      s[r] += v; q[r] += v * v;
    }
  }
#pragma unroll
  for (int off = 1; off < 16; off <<= 1) {
#pragma unroll
    for (int r = 0; r < 4; ++r) {
      s[r] += __shfl_xor(s[r], off);
      q[r] += __shfl_xor(q[r], off);
    }
  }
  // acc[jt][r] -> y (LN+ReLU), in place
#pragma unroll
  for (int r = 0; r < 4; ++r) {
    float mu = s[r] * 0.0078125f;
    float var = q[r] * 0.0078125f - mu * mu;
    float rstd = rsqrtf(var + 1e-5f);
#pragma unroll
    for (int jt = 0; jt < 8; ++jt) {
      float y = (acc[jt][r] - mu) * rstd * gv[jt] + bev[jt];
      acc[jt][r] = fmaxf(y, 0.f);
    }
  }

  // ---- epilogue: coalesced store via LDS staging (lA reused) ----
  __syncthreads();  // everyone done reading mean frags
  int lrow0 = wave * 16 + kgp * 4;  // local rows this thread covers: lrow0..lrow0+3
  if (out_f == nullptr) {
    // bf16: full 64x128 tile = 16 KB = 1024 uint4, single pass
    ushort* ls = lA;
#pragma unroll
    for (int r = 0; r < 4; ++r)
#pragma unroll
      for (int jt = 0; jt < 8; ++jt)
        ls[(lrow0 + r) * 128 + jt * 16 + m] = f2bf(acc[jt][r]);
    __syncthreads();
    const uint4* lsv = reinterpret_cast<const uint4*>(lA);
    uint4* ob = reinterpret_cast<uint4*>(out_b) + (size_t)blockIdx.x * 1024;
#pragma unroll
    for (int i = 0; i < 4; ++i) {
      int ci = t + i * 256;                 // 0..1023, 16 uint4 per row
      int row = blockIdx.x * 64 + (ci >> 4);
      if (row < N) ob[ci] = lsv[ci];
    }
  } else {
    // f32: two passes of 32x128 floats = 16 KB each
    float* lf = reinterpret_cast<float*>(lA);
#pragma unroll
    for (int h = 0; h < 2; ++h) {
      if ((wave >> 1) == h) {
#pragma unroll
        for (int r = 0; r < 4; ++r)
#pragma unroll
          for (int jt = 0; jt < 8; ++jt)
            lf[(lrow0 - h * 32 + r) * 128 + jt * 16 + m] = acc[jt][r];
      }
      __syncthreads();
      const float4* lfv = reinterpret_cast<const float4*>(lA);
      float4* of = reinterpret_cast<float4*>(out_f) +
                   ((size_t)blockIdx.x * 64 + h * 32) * 32;
#pragma unroll
      for (int i = 0; i < 4; ++i) {
        int ci = t + i * 256;               // 0..1023, 32 float4 per row
        int row = blockIdx.x * 64 + h * 32 + (ci >> 5);
        if (row < N) of[ci] = lfv[ci];
      }
      __syncthreads();
    }
  }
}

extern "C" void kernel_launch(void* const* d_in, const int* in_sizes, int n_in,
                              void* d_out, int out_size, void* d_ws, size_t ws_size,
                              hipStream_t stream) {
  const float* x   = (const float*)d_in[0];
  const int*   ei  = (const int*)d_in[1];
  const float* Wl0 = (const float*)d_in[2];
  const float* bl0 = (const float*)d_in[3];
  const float* Wr0 = (const float*)d_in[4];
  const float* g0  = (const float*)d_in[5];
  const float* be0 = (const float*)d_in[6];
  const float* Wl  = (const float*)d_in[7];
  const float* bls = (const float*)d_in[8];
  const float* Wr  = (const float*)d_in[9];
  const float* gs  = (const float*)d_in[10];
  const float* bes = (const float*)d_in[11];

  int N = in_sizes[0] / 128;
  int E = in_sizes[1] / 2;
  int Np = (N + 127) & ~127;
  int nbuck = (N + NPB - 1) / NPB;
  const int* srcv = ei;
  const int* dstv = ei + E;

  char* p = (char*)d_ws;
  auto alloc = [&](size_t bytes) {
    char* r = p;
    p += (bytes + 255) & ~(size_t)255;
    return r;
  };
  ushort* xb  = (ushort*)alloc((size_t)(Np + 16) * 128 * 2);
  ushort* hb  = (ushort*)alloc((size_t)(Np + 16) * 128 * 2);
  ushort* Wsw = (ushort*)alloc((size_t)3 * 64 * 64 * 8 * 2);
  int*   cntm      = (int*)alloc((size_t)nbuck * PART_BLOCKS * 4);
  int*   blocksums = (int*)alloc(8192);
  int*   row_start = (int*)alloc((size_t)N * 4);
  int*   nchunks   = (int*)alloc((size_t)N * 4);
  float* inv_deg   = (float*)alloc((size_t)N * 4);
  uint*  part      = (uint*)alloc((size_t)E * 4);
  int*   csr_pad   = (int*)alloc(((size_t)E + (size_t)nbuck * BSLACK + 256) * 4);

  int n4 = N * 32;
  int nCast = (n4 + 255) / 256;
  // prep: cast + swizzle + sentinel + histogram, one kernel
  k_prep<<<nCast + 49 + PART_BLOCKS, 256, 0, stream>>>(
      x, xb, hb, Wl0, Wr0, Wl, Wr, Wsw, dstv, cntm, E, n4, nCast, N, nbuck);

  int nscan = nbuck * PART_BLOCKS;
  int nScanBlocks = (nscan + 1023) / 1024;
  k_scan_a<<<nScanBlocks, 256, 0, stream>>>(cntm, cntm, blocksums, nscan);
  k_partition<<<PART_BLOCKS, 256, 0, stream>>>(srcv, dstv, cntm, blocksums, part, E,
                                               nbuck, nScanBlocks);
  k_build<<<nbuck, 256, 0, stream>>>(part, cntm, blocksums, row_start, nchunks, inv_deg,
                                     csr_pad, E, N, nbuck, nScanBlocks);

  dim3 grid((N + 63) / 64);
  // layer 0: src=xb -> out hb (bf16)
  k_layer<<<grid, 256, 0, stream>>>(xb, row_start, nchunks, inv_deg, csr_pad,
                                    Wsw + 0 * 32768, bl0, g0, be0, hb, nullptr, N);
  // layer 1: src=hb -> out xb (bf16)
  k_layer<<<grid, 256, 0, stream>>>(hb, row_start, nchunks, inv_deg, csr_pad,
                                    Wsw + 1 * 32768, bls + 0, gs + 0, bes + 0,
                                    xb, nullptr, N);
  // layer 2: src=xb -> out d_out (f32)
  k_layer<<<grid, 256, 0, stream>>>(xb, row_start, nchunks, inv_deg, csr_pad,
                                    Wsw + 2 * 32768, bls + 128, gs + 128, bes + 128,
                                    nullptr, (float*)d_out, N);
}